// Round 11
// baseline (592.419 us; speedup 1.0000x reference)
//
#include <hip/hip_runtime.h>
#include <hip/hip_bf16.h>
#include <hip/hip_fp16.h>
#if __has_include(<hip/hip_fp8.h>)
#include <hip/hip_fp8.h>
#endif
#include <math.h>

#define N 8192
#define D 128
#define CAP 512   // max stored neighbors per row (true max deg ~165+13*sigma)

typedef _Float16 f16x2 __attribute__((ext_vector_type(2)));
typedef _Float16 f16x4 __attribute__((ext_vector_type(4)));
typedef _Float16 f16x8 __attribute__((ext_vector_type(8)));
typedef float    f32x2 __attribute__((ext_vector_type(2)));
typedef float    f32x4 __attribute__((ext_vector_type(4)));

// ---- fp8 e4m3 pack/unpack (HW cvt on gfx950; OCP format) ----
__device__ __forceinline__ unsigned pack_fp8x4(float4 a) {
#if __has_builtin(__builtin_amdgcn_cvt_pk_fp8_f32)
    int w = __builtin_amdgcn_cvt_pk_fp8_f32(a.x, a.y, 0, false);
    w = __builtin_amdgcn_cvt_pk_fp8_f32(a.z, a.w, w, true);
    return (unsigned)w;
#else
    __hip_fp8_e4m3 b0(a.x), b1(a.y), b2(a.z), b3(a.w);
    return (unsigned)b0.__x | ((unsigned)b1.__x << 8) |
           ((unsigned)b2.__x << 16) | ((unsigned)b3.__x << 24);
#endif
}

template <bool HI>
__device__ __forceinline__ f32x2 unpack_fp8x2(unsigned w) {
#if __has_builtin(__builtin_amdgcn_cvt_pk_f32_fp8)
    return __builtin_amdgcn_cvt_pk_f32_fp8((int)w, HI);   // HI is a literal constant
#else
    unsigned sh = HI ? 16 : 0;
    __hip_fp8_e4m3 a, b;
    a.__x = (unsigned char)(w >> sh);
    b.__x = (unsigned char)(w >> (sh + 8));
    f32x2 r; r[0] = (float)a; r[1] = (float)b;
    return r;
#endif
}

// ---------------------------------------------------------------------------
// FUSED: adjacency build (blocks 0..N-1) + layer-0 Q/K/V projection
// (blocks N..N+N/8-1). Mask scan (BW-bound) overlaps QKV GEMM (VALU-bound).
// K/V stored fp8 e4m3, INTERLEAVED: KV8[j] = [K 128B | V 128B] = 256 B
// = ONE 16-lane-group segment (R11: whole edge in one load instruction).
// ---------------------------------------------------------------------------
__global__ __launch_bounds__(256) void adj_qkv(const int* __restrict__ mask,
                                               unsigned short* __restrict__ nbr,
                                               int* __restrict__ deg,
                                               const float* __restrict__ A,
                                               const float* __restrict__ Wq, const float* __restrict__ bq,
                                               const float* __restrict__ Wk, const float* __restrict__ bk,
                                               const float* __restrict__ Wv, const float* __restrict__ bv,
                                               __half* __restrict__ Qo,
                                               unsigned char* __restrict__ KV8,
                                               float* __restrict__ copy_out) {
    __shared__ float As[8][D];
    const int tid = threadIdx.x;

    if (blockIdx.x < N) {
        // ---- adjacency build (row-local LDS counter) ----
        const int i = blockIdx.x;
        __shared__ int cnt;
        if (tid == 0) cnt = 0;
        __syncthreads();
        const int4* row = (const int4*)(mask + (size_t)i * N);
        for (int c = tid; c < N / 4; c += 256) {
            int4 m4 = row[c];
            int base = 4 * c;
            if (m4.x) { int p = atomicAdd(&cnt, 1); if (p < CAP) nbr[(size_t)i * CAP + p] = (unsigned short)(base); }
            if (m4.y) { int p = atomicAdd(&cnt, 1); if (p < CAP) nbr[(size_t)i * CAP + p] = (unsigned short)(base + 1); }
            if (m4.z) { int p = atomicAdd(&cnt, 1); if (p < CAP) nbr[(size_t)i * CAP + p] = (unsigned short)(base + 2); }
            if (m4.w) { int p = atomicAdd(&cnt, 1); if (p < CAP) nbr[(size_t)i * CAP + p] = (unsigned short)(base + 3); }
        }
        __syncthreads();
        if (tid == 0) deg[i] = (cnt > CAP) ? CAP : cnt;
        return;
    }

    // ---- layer-0 QKV projection + fused output-0 copy ----
    const int r   = tid >> 5;
    const int jg  = tid & 31;
    const int i0  = (blockIdx.x - N) * 8;

    const float4 av = ((const float4*)(A + (size_t)i0 * D))[tid];
    ((float4*)&As[0][0])[tid] = av;
    ((float4*)(copy_out + (size_t)i0 * D))[tid] = av;
    __syncthreads();

    const float* Ws[3] = {Wq, Wk, Wv};
    const float* bs[3] = {bq, bk, bv};

    #pragma unroll
    for (int m = 0; m < 3; ++m) {
        float4 acc = *(const float4*)(bs[m] + 4 * jg);
        const float* W = Ws[m];
        #pragma unroll 8
        for (int k4 = 0; k4 < 32; ++k4) {
            const float4 a4 = *(const float4*)&As[r][4 * k4];
            const float* wb = W + (size_t)(4 * k4) * D + 4 * jg;
            const float4 w0 = *(const float4*)(wb);
            const float4 w1 = *(const float4*)(wb + D);
            const float4 w2 = *(const float4*)(wb + 2 * D);
            const float4 w3 = *(const float4*)(wb + 3 * D);
            acc.x += a4.x * w0.x + a4.y * w1.x + a4.z * w2.x + a4.w * w3.x;
            acc.y += a4.x * w0.y + a4.y * w1.y + a4.z * w2.y + a4.w * w3.y;
            acc.z += a4.x * w0.z + a4.y * w1.z + a4.z * w2.z + a4.w * w3.z;
            acc.w += a4.x * w0.w + a4.y * w1.w + a4.z * w2.w + a4.w * w3.w;
        }
        if (m == 0) {
            f16x4 h;
            h[0] = (_Float16)acc.x; h[1] = (_Float16)acc.y;
            h[2] = (_Float16)acc.z; h[3] = (_Float16)acc.w;
            *(f16x4*)(Qo + (size_t)(i0 + r) * D + 4 * jg) = h;
        } else {
            *(unsigned*)(KV8 + (size_t)(i0 + r) * 256 + (m == 1 ? 0 : 128) + 4 * jg) =
                pack_fp8x4(acc);
        }
    }
}

// ---------------------------------------------------------------------------
// Fused layer boundary: h = Aattn@Wo + bo -> Hout, then next layer's Q/K/V
// (Q fp16, K/V fp8 interleaved).
// ---------------------------------------------------------------------------
__global__ __launch_bounds__(256) void gemmO_qkv(const float* __restrict__ Aattn,
                                                 const float* __restrict__ Wo, const float* __restrict__ bo,
                                                 float* __restrict__ Hout,
                                                 const float* __restrict__ Wq, const float* __restrict__ bq,
                                                 const float* __restrict__ Wk, const float* __restrict__ bk,
                                                 const float* __restrict__ Wv, const float* __restrict__ bv,
                                                 __half* __restrict__ Qo,
                                                 unsigned char* __restrict__ KV8) {
    __shared__ float As[8][D];
    __shared__ float Hs[8][D];
    const int tid = threadIdx.x;
    const int r   = tid >> 5;
    const int jg  = tid & 31;
    const int i0  = blockIdx.x * 8;

    ((float4*)&As[0][0])[tid] = ((const float4*)(Aattn + (size_t)i0 * D))[tid];
    __syncthreads();

    {
        float4 acc = *(const float4*)(bo + 4 * jg);
        #pragma unroll 8
        for (int k4 = 0; k4 < 32; ++k4) {
            const float4 a4 = *(const float4*)&As[r][4 * k4];
            const float* wb = Wo + (size_t)(4 * k4) * D + 4 * jg;
            const float4 w0 = *(const float4*)(wb);
            const float4 w1 = *(const float4*)(wb + D);
            const float4 w2 = *(const float4*)(wb + 2 * D);
            const float4 w3 = *(const float4*)(wb + 3 * D);
            acc.x += a4.x * w0.x + a4.y * w1.x + a4.z * w2.x + a4.w * w3.x;
            acc.y += a4.x * w0.y + a4.y * w1.y + a4.z * w2.y + a4.w * w3.y;
            acc.z += a4.x * w0.z + a4.y * w1.z + a4.z * w2.z + a4.w * w3.z;
            acc.w += a4.x * w0.w + a4.y * w1.w + a4.z * w2.w + a4.w * w3.w;
        }
        *(float4*)(Hout + (size_t)(i0 + r) * D + 4 * jg) = acc;
        *(float4*)&Hs[r][4 * jg] = acc;
    }
    __syncthreads();

    const float* Ws[3] = {Wq, Wk, Wv};
    const float* bs[3] = {bq, bk, bv};
    #pragma unroll
    for (int m = 0; m < 3; ++m) {
        float4 acc = *(const float4*)(bs[m] + 4 * jg);
        const float* W = Ws[m];
        #pragma unroll 8
        for (int k4 = 0; k4 < 32; ++k4) {
            const float4 a4 = *(const float4*)&Hs[r][4 * k4];
            const float* wb = W + (size_t)(4 * k4) * D + 4 * jg;
            const float4 w0 = *(const float4*)(wb);
            const float4 w1 = *(const float4*)(wb + D);
            const float4 w2 = *(const float4*)(wb + 2 * D);
            const float4 w3 = *(const float4*)(wb + 3 * D);
            acc.x += a4.x * w0.x + a4.y * w1.x + a4.z * w2.x + a4.w * w3.x;
            acc.y += a4.x * w0.y + a4.y * w1.y + a4.z * w2.y + a4.w * w3.y;
            acc.z += a4.x * w0.z + a4.y * w1.z + a4.z * w2.z + a4.w * w3.z;
            acc.w += a4.x * w0.w + a4.y * w1.w + a4.z * w2.w + a4.w * w3.w;
        }
        if (m == 0) {
            f16x4 h;
            h[0] = (_Float16)acc.x; h[1] = (_Float16)acc.y;
            h[2] = (_Float16)acc.z; h[3] = (_Float16)acc.w;
            *(f16x4*)(Qo + (size_t)(i0 + r) * D + 4 * jg) = h;
        } else {
            *(unsigned*)(KV8 + (size_t)(i0 + r) * 256 + (m == 1 ? 0 : 128) + 4 * jg) =
                pack_fp8x4(acc);
        }
    }
}

// ---------------------------------------------------------------------------
// Final output projection (fp32 in/out).
// ---------------------------------------------------------------------------
__global__ __launch_bounds__(256) void gemm_bias(const float* __restrict__ A,
                                                 const float* __restrict__ W,
                                                 const float* __restrict__ bias,
                                                 float* __restrict__ C) {
    __shared__ float As[8][D];
    const int tid = threadIdx.x;
    const int r   = tid >> 5;
    const int jg  = tid & 31;
    const int i0  = blockIdx.x * 8;

    ((float4*)&As[0][0])[tid] = ((const float4*)(A + (size_t)i0 * D))[tid];
    __syncthreads();

    float4 acc = *(const float4*)(bias + 4 * jg);
    #pragma unroll 8
    for (int k4 = 0; k4 < 32; ++k4) {
        const float4 a4 = *(const float4*)&As[r][4 * k4];
        const float* wb = W + (size_t)(4 * k4) * D + 4 * jg;
        const float4 w0 = *(const float4*)(wb);
        const float4 w1 = *(const float4*)(wb + D);
        const float4 w2 = *(const float4*)(wb + 2 * D);
        const float4 w3 = *(const float4*)(wb + 3 * D);
        acc.x += a4.x * w0.x + a4.y * w1.x + a4.z * w2.x + a4.w * w3.x;
        acc.y += a4.x * w0.y + a4.y * w1.y + a4.z * w2.y + a4.w * w3.y;
        acc.z += a4.x * w0.z + a4.y * w1.z + a4.z * w2.z + a4.w * w3.z;
        acc.w += a4.x * w0.w + a4.y * w1.w + a4.z * w2.w + a4.w * w3.w;
    }
    *(float4*)(C + (size_t)(i0 + r) * D + 4 * jg) = acc;
}

// ---------------------------------------------------------------------------
// Sparse masked attention, R11: ONE LOAD INSTRUCTION PER EDGE.
// R10's decisive null (fp8 = fp16 time despite halved bytes/lines) killed
// the byte/line model; surviving model: the binder is divergent-address
// REQUEST processing (~36 cyc per 16-lane-group segment per CU, size-
// independent 128-256B). Every prior round used 2 requests/edge (K, V).
// This round: fp8 KV row = 256 B = exactly one group segment -> lane gl
// reads uint4 at row+16*gl; lanes 0-7 hold all of K, lanes 8-15 all of V.
// Dot on lanes 0-7 (16 dims/lane, shfl 1/2/4 within the 8-lane half);
// shfl_xor(8) broadcasts the dot to the V half. PV accumulates on lanes
// 8-15; lanes 0-7 accumulate garbage that is never read (lane-position-
// preserving cross-group reduce keeps halves separate). Requests/edge: 1.
// ---------------------------------------------------------------------------
__global__ __launch_bounds__(256, 6) void attn_sparse(const __half* __restrict__ Q,
                                                      const unsigned char* __restrict__ KV8,
                                                      const unsigned short* __restrict__ nbr,
                                                      const int* __restrict__ deg,
                                                      float* __restrict__ Hout) {
    const int tid  = threadIdx.x;
    const int wave = tid >> 6;
    const int lane = tid & 63;
    const int g    = lane >> 4;   // 4 groups of 16 lanes; one edge per group per iter
    const int gl   = lane & 15;   // lane-in-group
    const int hl   = gl & 7;      // half-lane: owns dims [16*hl, 16*hl+16)
    const int i    = blockIdx.x * 4 + wave;

    __shared__ unsigned short jls[4][CAP];

    const int dg = min(deg[i], CAP);
    for (int e = lane; e < dg; e += 64)
        jls[wave][e] = __builtin_nontemporal_load(&nbr[(size_t)i * CAP + e]);

    // Q dims [16*hl, 16*hl+16) hoisted to f32 (both halves load the same dims)
    float qf[16];
    {
        const f16x8* qp = (const f16x8*)(Q + (size_t)i * D + 16 * hl);
        const f16x8 q0 = qp[0], q1 = qp[1];
        #pragma unroll
        for (int k = 0; k < 8; ++k) { qf[k] = (float)q0[k]; qf[8 + k] = (float)q1[k]; }
    }
    __syncthreads();   // only barrier: jls visible to the wave

    const float scale = 0.088388347648318447f;  // 1/sqrt(128)

    float acc[16];
    #pragma unroll
    for (int k = 0; k < 16; ++k) acc[k] = 0.f;
    float denom = 0.f;

    for (int e = g; e < dg; e += 4) {
        const int j = jls[wave][e];                 // uniform per group: LDS broadcast
        // ONE instruction, one 256B segment per group: K->lanes 0-7, V->lanes 8-15
        const uint4 d4 = *(const uint4*)(KV8 + (size_t)j * 256 + 16 * gl);

        const f32x2 u0 = unpack_fp8x2<false>(d4.x), u1 = unpack_fp8x2<true>(d4.x);
        const f32x2 u2 = unpack_fp8x2<false>(d4.y), u3 = unpack_fp8x2<true>(d4.y);
        const f32x2 u4 = unpack_fp8x2<false>(d4.z), u5 = unpack_fp8x2<true>(d4.z);
        const f32x2 u6 = unpack_fp8x2<false>(d4.w), u7 = unpack_fp8x2<true>(d4.w);
        const float v[16] = {u0[0], u0[1], u1[0], u1[1], u2[0], u2[1], u3[0], u3[1],
                             u4[0], u4[1], u5[0], u5[1], u6[0], u6[1], u7[0], u7[1]};

        // dot partial: meaningful on gl<8 (K data); garbage on gl>=8 (discarded)
        float d0 = 0.f, d1 = 0.f;
        #pragma unroll
        for (int k = 0; k < 16; k += 2) { d0 += qf[k] * v[k]; d1 += qf[k + 1] * v[k + 1]; }
        float dot = d0 + d1;
        dot += __shfl_xor(dot, 1);
        dot += __shfl_xor(dot, 2);
        dot += __shfl_xor(dot, 4);                  // lanes 0-7 of group: true full dot
        const float oth = __shfl_xor(dot, 8);       // broadcast across halves
        const float dv  = (gl & 8) ? oth : dot;     // all 16 lanes: true dot
        const float p   = __expf(dv * scale);

        // PV: true V on lanes 8-15; lanes 0-7 accumulate garbage (never read)
        #pragma unroll
        for (int k = 0; k < 16; ++k) acc[k] += p * v[k];
        denom += p;                                 // identical across the group
    }

    // cross-group combine (lane-position-preserving: halves stay separate)
    #pragma unroll
    for (int k = 0; k < 16; ++k) {
        acc[k] += __shfl_xor(acc[k], 16);
        acc[k] += __shfl_xor(acc[k], 32);
    }
    denom += __shfl_xor(denom, 16);
    denom += __shfl_xor(denom, 32);

    if (g == 0 && (gl & 8)) {                       // 8 lanes write 16 dims each
        const float inv = 1.0f / denom;
        float* dst = Hout + (size_t)i * D + 16 * hl;
        #pragma unroll
        for (int q4 = 0; q4 < 4; ++q4) {
            f32x4 o;
            o[0] = acc[4 * q4]     * inv; o[1] = acc[4 * q4 + 1] * inv;
            o[2] = acc[4 * q4 + 2] * inv; o[3] = acc[4 * q4 + 3] * inv;
            __builtin_nontemporal_store(o, (f32x4*)(dst + 4 * q4));
        }
    }
}

extern "C" void kernel_launch(void* const* d_in, const int* in_sizes, int n_in,
                              void* d_out, int out_size, void* d_ws, size_t ws_size,
                              hipStream_t stream) {
    const float* features = (const float*)d_in[0];
    const int*   mask     = (const int*)d_in[1];
    const float* Wq = (const float*)d_in[2];
    const float* bq = (const float*)d_in[3];
    const float* Wk = (const float*)d_in[4];
    const float* bk = (const float*)d_in[5];
    const float* Wv = (const float*)d_in[6];
    const float* bv = (const float*)d_in[7];
    const float* Wo = (const float*)d_in[8];
    const float* bo = (const float*)d_in[9];
    float* out = (float*)d_out;

    // workspace layout (~16 MB): nbr | deg | Q(f16) | KV8(fp8) | tmp
    char* base = (char*)d_ws;
    unsigned short* nbr = (unsigned short*)base;                        // 8 MB
    int*    deg  = (int*)(base + (size_t)N * CAP * 2);                  // 32 KB
    __half* Qb16 = (__half*)(base + (size_t)N * CAP * 2 + N * 4);       // 2 MB
    unsigned char* KV8 = (unsigned char*)(Qb16 + (size_t)N * D);        // 2 MB (K|V fp8)
    float*  tmp  = (float*)(KV8 + (size_t)N * 256);                     // 4 MB

    // fused adjacency + layer-0 QKV (+ out[0] copy)
    adj_qkv<<<N + N / 8, 256, 0, stream>>>(mask, nbr, deg,
                                           features, Wq, bq, Wk, bk, Wv, bv,
                                           Qb16, KV8, out);
    attn_sparse<<<N / 4, 256, 0, stream>>>(Qb16, KV8, nbr, deg, tmp);
    gemmO_qkv<<<N / 8, 256, 0, stream>>>(tmp, Wo, bo, out + (size_t)N * D,
                                         Wq + D * D, bq + D, Wk + D * D, bk + D,
                                         Wv + D * D, bv + D, Qb16, KV8);
    // layer 1
    attn_sparse<<<N / 4, 256, 0, stream>>>(Qb16, KV8, nbr, deg, tmp);
    gemm_bias<<<N / 8, 256, 0, stream>>>(tmp, Wo + D * D, bo + D,
                                         out + (size_t)2 * N * D);
}